// Round 5
// baseline (252.185 us; speedup 1.0000x reference)
//
#include <hip/hip_runtime.h>

// TrajLoss: sum over i of (x[i]-pred[i])^2 + (y[i]-pred[i+1])^2
// N = 16,777,216; pred has N+1 elements. Memory-bound streaming reduction.
//
// R4: drop the redundant shifted pred stream. Lane l needs pred[4i+4] only
// for its last element's dy — that value is the NEXT lane's pa.x. Get it via
// __shfl_down(pa.x,1); lane 63 (or last active lane) does one predicated
// scalar load. vmem wave-insts per iter: 4 -> 3, all 16B-aligned.

typedef float fx4 __attribute__((ext_vector_type(4)));

__global__ void TrajLoss_zero_kernel(float* out) {
    if (threadIdx.x == 0 && blockIdx.x == 0) out[0] = 0.0f;
}

__global__ __launch_bounds__(256) void TrajLoss_6141803233879_kernel(
    const float* __restrict__ pred,
    const float* __restrict__ x,
    const float* __restrict__ y,
    float* __restrict__ out,
    int n4,   // n / 4 (float4 count)
    int n)    // total elements
{
    const int tid    = blockIdx.x * blockDim.x + threadIdx.x;
    const int stride = gridDim.x * blockDim.x;
    const int lane   = threadIdx.x & 63;

    float a0 = 0.0f, a1 = 0.0f, a2 = 0.0f, a3 = 0.0f;
    const fx4* x4 = (const fx4*)x;
    const fx4* y4 = (const fx4*)y;
    const fx4* p4 = (const fx4*)pred;

    #pragma unroll 2
    for (int i = tid; i < n4; i += stride) {
        fx4 xv = __builtin_nontemporal_load(x4 + i);
        fx4 yv = __builtin_nontemporal_load(y4 + i);
        fx4 pa = p4[i];                       // pred[4i .. 4i+3]

        // pred[4i+4]: next lane's pa.x (grid-stride => lane l+1 holds i+1).
        float nx = __shfl_down(pa.x, 1, 64);
        if (lane == 63 || i + 1 >= n4)        // no valid donor lane
            nx = pred[(i << 2) + 4];          // 1 line request per wave

        float dx, dy;
        dx = xv.x - pa.x; dy = yv.x - pa.y; a0 += dx*dx + dy*dy;
        dx = xv.y - pa.y; dy = yv.y - pa.z; a1 += dx*dx + dy*dy;
        dx = xv.z - pa.z; dy = yv.z - pa.w; a2 += dx*dx + dy*dy;
        dx = xv.w - pa.w; dy = yv.w - nx;   a3 += dx*dx + dy*dy;
    }

    float acc = (a0 + a1) + (a2 + a3);

    // Scalar tail (n not divisible by 4) — dead code for N=16.7M.
    if (tid == 0) {
        for (int j = n4 << 2; j < n; ++j) {
            float dx = x[j] - pred[j];
            float dy = y[j] - pred[j + 1];
            acc += dx * dx + dy * dy;
        }
    }

    // Wave-64 reduce
    #pragma unroll
    for (int off = 32; off > 0; off >>= 1)
        acc += __shfl_down(acc, off, 64);

    __shared__ float smem[4];   // 256 threads = 4 waves
    const int wave = threadIdx.x >> 6;
    if (lane == 0) smem[wave] = acc;
    __syncthreads();

    if (threadIdx.x == 0) {
        float s = smem[0] + smem[1] + smem[2] + smem[3];
        atomicAdd(out, s);   // device-scope by default on gfx950
    }
}

extern "C" void kernel_launch(void* const* d_in, const int* in_sizes, int n_in,
                              void* d_out, int out_size, void* d_ws, size_t ws_size,
                              hipStream_t stream) {
    const float* pred = (const float*)d_in[0];   // N+1 floats
    const float* x    = (const float*)d_in[1];   // N floats
    const float* y    = (const float*)d_in[2];   // N floats
    float* out = (float*)d_out;

    const int n  = in_sizes[1];
    const int n4 = n >> 2;

    TrajLoss_zero_kernel<<<1, 64, 0, stream>>>(out);

    const int block = 256;
    const int grid = 8192;   // 2,097,152 threads -> exactly 2 float4 iters/thread
    TrajLoss_6141803233879_kernel<<<grid, block, 0, stream>>>(pred, x, y, out, n4, n);
}

// Round 6
// 196.506 us; speedup vs baseline: 1.2833x; 1.2833x over previous
//
#include <hip/hip_runtime.h>

// TrajLoss: sum over i of (x[i]-pred[i])^2 + (y[i]-pred[i+1])^2
// N = 16,777,216; pred has N+1 elements. Memory-bound streaming reduction.
//
// R5: algebraic re-split. Sum_i (y_i - p_{i+1})^2 == Sum_{j=1..N} (y_{j-1} - p_j)^2,
// so the thread owning pred[4i..4i+3] needs only:
//   x4[i] (aligned), p4[i] (aligned), y[4i-1..4i+2] (one unaligned dwordx4).
// 3 vmem insts per 48 useful bytes/lane (R3 needed 4: pred was read through two
// shifted views). Edge terms (j=0..3, j=N) peeled into a thread-0 scalar
// prologue so the hot loop is branch-free (R4 lesson: per-iter divergence +
// cross-lane data deps collapse the scheduler).

typedef float fx4 __attribute__((ext_vector_type(4)));

__global__ void TrajLoss_zero_kernel(float* out) {
    if (threadIdx.x == 0 && blockIdx.x == 0) out[0] = 0.0f;
}

__global__ __launch_bounds__(256) void TrajLoss_6141803233879_kernel(
    const float* __restrict__ pred,
    const float* __restrict__ x,
    const float* __restrict__ y,
    float* __restrict__ out,
    int n4,   // n / 4 (float4 count)
    int n)    // total elements
{
    const int tid    = blockIdx.x * blockDim.x + threadIdx.x;
    const int stride = gridDim.x * blockDim.x;

    float a0 = 0.0f, a1 = 0.0f, a2 = 0.0f, a3 = 0.0f;
    const fx4* x4 = (const fx4*)x;
    const fx4* p4 = (const fx4*)pred;

    int i = tid;

    if (tid == 0) {
        // Peel chunk 0 (rewrite terms j=0..3: dx_0..3, dy_1..3) + boundary j=N.
        float dx, dy;
        dx = x[0] - pred[0];                       a0 += dx*dx;
        dx = x[1] - pred[1]; dy = y[0] - pred[1];  a1 += dx*dx + dy*dy;
        dx = x[2] - pred[2]; dy = y[1] - pred[2];  a2 += dx*dx + dy*dy;
        dx = x[3] - pred[3]; dy = y[2] - pred[3];  a3 += dx*dx + dy*dy;
        if ((n & 3) == 0) {
            dy = y[n - 1] - pred[n];               a0 += dy*dy;   // rewrite j=N
        } else {
            // generic tail (dead for N=16.7M): cover rewrite j=4*n4 then
            // original-form scalars for j in [4*n4, n)
            dy = y[(n4 << 2) - 1] - pred[n4 << 2]; a0 += dy*dy;
            for (int j = n4 << 2; j < n; ++j) {
                dx = x[j] - pred[j];
                dy = y[j] - pred[j + 1];
                a0 += dx*dx + dy*dy;
            }
        }
        i += stride;   // thread 0 skips its first generic chunk (handled above)
    }

    #pragma unroll 4
    for (; i < n4; i += stride) {
        fx4 xv = __builtin_nontemporal_load(x4 + i);
        fx4 pa = p4[i];                               // pred[4i .. 4i+3]
        fx4 yb = *(const fx4*)(y + (i << 2) - 1);     // y[4i-1 .. 4i+2], 4B-aligned
        float dx, dy;
        dx = xv.x - pa.x; dy = yb.x - pa.x; a0 += dx*dx + dy*dy;
        dx = xv.y - pa.y; dy = yb.y - pa.y; a1 += dx*dx + dy*dy;
        dx = xv.z - pa.z; dy = yb.z - pa.z; a2 += dx*dx + dy*dy;
        dx = xv.w - pa.w; dy = yb.w - pa.w; a3 += dx*dx + dy*dy;
    }

    float acc = (a0 + a1) + (a2 + a3);

    // Wave-64 reduce
    #pragma unroll
    for (int off = 32; off > 0; off >>= 1)
        acc += __shfl_down(acc, off, 64);

    __shared__ float smem[4];   // 256 threads = 4 waves
    const int lane = threadIdx.x & 63;
    const int wave = threadIdx.x >> 6;
    if (lane == 0) smem[wave] = acc;
    __syncthreads();

    if (threadIdx.x == 0) {
        float s = smem[0] + smem[1] + smem[2] + smem[3];
        atomicAdd(out, s);   // device-scope by default on gfx950
    }
}

extern "C" void kernel_launch(void* const* d_in, const int* in_sizes, int n_in,
                              void* d_out, int out_size, void* d_ws, size_t ws_size,
                              hipStream_t stream) {
    const float* pred = (const float*)d_in[0];   // N+1 floats
    const float* x    = (const float*)d_in[1];   // N floats
    const float* y    = (const float*)d_in[2];   // N floats
    float* out = (float*)d_out;

    const int n  = in_sizes[1];
    const int n4 = n >> 2;

    TrajLoss_zero_kernel<<<1, 64, 0, stream>>>(out);

    const int block = 256;
    const int grid = 4096;   // 1,048,576 threads -> 4 float4 chunks/thread
    TrajLoss_6141803233879_kernel<<<grid, block, 0, stream>>>(pred, x, y, out, n4, n);
}